// Round 3
// baseline (269.510 us; speedup 1.0000x reference)
//
#include <hip/hip_runtime.h>

#define CC 256
#define EE 128
#define BB 8
#define NN 3136
#define NN4 784      // NN / 4 (float4 per row)
#define T4 8         // float4 per i-tile (32 spatial positions)
#define NTILES 98    // tiles per batch image
#define GRID 392     // 2 tiles per block; 392 <= 4 blocks/CU * 256 CU => all co-resident
#define SCOPE __HIP_MEMORY_SCOPE_AGENT

__device__ __forceinline__ float waveReduceSum(float v) {
    #pragma unroll
    for (int off = 32; off > 0; off >>= 1) v += __shfl_down(v, off, 64);
    return v;
}

// Single kernel, manual (provably co-resident) grid barrier.
//  W   (block 391): A[c] = Wcat[:E]·Wq[:,c] + Wcat[E:]·Wk[:,c]; cst  -> release stores
//  X   (all, strided): xbar[row] = mean_i x[row,i]                   -> release stores
//  BAR : counter spin (cnt memset to 0 pre-launch)
//  G   (per block, redundant, inputs only): u = Wv·xbar_b + bv; g = Wexp·u
//  OUT (2 tiles per block): s[i] = relu(A·x[b,:,i] + cst); out = x + s*g + bexp
__global__ void __launch_bounds__(256, 4) mega(
        const float* __restrict__ x,
        const float* __restrict__ Wq, const float* __restrict__ bq,
        const float* __restrict__ Wk, const float* __restrict__ bk,
        const float* __restrict__ Wv, const float* __restrict__ bv,
        const float* __restrict__ Wcat, const float* __restrict__ Wexp,
        const float* __restrict__ bexp, float* __restrict__ out,
        float* __restrict__ xbar, float* __restrict__ Ag,
        float* __restrict__ cstg, unsigned int* __restrict__ cnt)
{
    const int blk = blockIdx.x, tid = threadIdx.x;
    const int wid = tid >> 6, lane = tid & 63;

    __shared__ float red[4];
    __shared__ float xb_s[CC];
    __shared__ float u_part[2][EE];
    __shared__ float u_s[EE];
    __shared__ float g_s[CC];
    __shared__ float A_s[CC];
    __shared__ float be_s[CC];
    __shared__ float cv_s;
    __shared__ float4 part[32][8];
    __shared__ float4 s_s[8];

    // ---- phase W: A & cst (block 391 only; overlaps phase X of others) ----
    if (blk == GRID - 1) {
        float a = 0.f;
        #pragma unroll 8
        for (int e = 0; e < EE; e++)
            a += Wcat[e] * Wq[e * CC + tid] + Wcat[EE + e] * Wk[e * CC + tid];
        __hip_atomic_store(&Ag[tid], a, __ATOMIC_RELEASE, SCOPE);
        if (tid < 64) {
            float cp = Wcat[tid] * bq[tid] + Wcat[tid + 64] * bq[tid + 64]
                     + Wcat[EE + tid] * bk[tid] + Wcat[EE + tid + 64] * bk[tid + 64];
            cp = waveReduceSum(cp);
            if (tid == 0) __hip_atomic_store(&cstg[0], cp, __ATOMIC_RELEASE, SCOPE);
        }
    }

    // ---- phase X: xbar rows, block-strided (coalesced full-row reads) ----
    for (int row = blk; row < BB * CC; row += GRID) {
        const float4* xr = (const float4*)(x + (size_t)row * NN);
        float acc = 0.f;
        for (int i = tid; i < NN4; i += 256) {
            float4 v = xr[i];
            acc += (v.x + v.y) + (v.z + v.w);
        }
        acc = waveReduceSum(acc);
        __syncthreads();                 // protect red[] from previous iter
        if (lane == 0) red[wid] = acc;
        __syncthreads();
        if (tid == 0)
            __hip_atomic_store(&xbar[row],
                               (red[0] + red[1] + red[2] + red[3]) * (1.0f / NN),
                               __ATOMIC_RELEASE, SCOPE);
    }

    // ---- barrier: all 392 blocks are co-resident by construction ----
    __syncthreads();                     // all waves' stores drained (vmcnt before s_barrier)
    if (tid == 0) {
        __threadfence();
        __hip_atomic_fetch_add(cnt, 1u, __ATOMIC_ACQ_REL, SCOPE);
        while (__hip_atomic_load(cnt, __ATOMIC_ACQUIRE, SCOPE) < (unsigned)GRID)
            __builtin_amdgcn_s_sleep(2);
    }
    __syncthreads();

    // ---- phase G: per-block gexp for this block's batch ----
    const int t0  = blk * 2;
    const int b   = t0 / NTILES;         // pair never straddles a batch (98 even)
    const int tl0 = t0 - b * NTILES;

    xb_s[tid] = __hip_atomic_load(&xbar[b * CC + tid], __ATOMIC_ACQUIRE, SCOPE);
    A_s[tid]  = __hip_atomic_load(&Ag[tid], __ATOMIC_ACQUIRE, SCOPE);
    be_s[tid] = bexp[tid];
    if (tid == 0) cv_s = __hip_atomic_load(&cstg[0], __ATOMIC_ACQUIRE, SCOPE);
    __syncthreads();

    {   // u_part[h][e] = sum over half-h of Wv[e,:]·xb  (inputs only, L2-hot)
        const int e = tid & 127, h = tid >> 7;
        const float4* wv4 = (const float4*)(Wv + (size_t)e * CC + h * 128);
        const float* xbh = xb_s + h * 128;
        float up = 0.f;
        #pragma unroll
        for (int i = 0; i < 32; i++) {
            float4 w = wv4[i];
            up = fmaf(w.x, xbh[i * 4 + 0], up);
            up = fmaf(w.y, xbh[i * 4 + 1], up);
            up = fmaf(w.z, xbh[i * 4 + 2], up);
            up = fmaf(w.w, xbh[i * 4 + 3], up);
        }
        u_part[h][e] = up;
    }
    __syncthreads();
    if (tid < EE) u_s[tid] = u_part[0][tid] + u_part[1][tid] + bv[tid];
    __syncthreads();
    {   // g_s[c] = Wexp[c,:]·u_s   (hg absorbed into u via bv)
        const float4* we4 = (const float4*)(Wexp + (size_t)tid * EE);
        float g = 0.f;
        #pragma unroll
        for (int i = 0; i < 32; i++) {
            float4 w = we4[i];
            g = fmaf(w.x, u_s[i * 4 + 0], g);
            g = fmaf(w.y, u_s[i * 4 + 1], g);
            g = fmaf(w.z, u_s[i * 4 + 2], g);
            g = fmaf(w.w, u_s[i * 4 + 3], g);
        }
        g_s[tid] = g;
    }
    __syncthreads();

    // ---- phase OUT: two tiles (x re-read is L3-warm from phase X) ----
    const int i4l = tid & 7, cgr = tid >> 3;
    const float4* xb4 = (const float4*)x + (size_t)b * CC * NN4;
    float4*       ob4 = (float4*)out    + (size_t)b * CC * NN4;

    for (int tt = 0; tt < 2; tt++) {
        const int tile = tl0 + tt;
        const float4* x4 = xb4 + tile * T4;
        float4*       o4 = ob4 + tile * T4;

        float4 xc[8];
        float4 acc4 = make_float4(0.f, 0.f, 0.f, 0.f);
        #pragma unroll
        for (int j = 0; j < 8; j++) {
            const int c = cgr * 8 + j;
            float4 v = x4[(size_t)c * NN4 + i4l];
            xc[j] = v;
            const float a = A_s[c];
            acc4.x = fmaf(a, v.x, acc4.x);
            acc4.y = fmaf(a, v.y, acc4.y);
            acc4.z = fmaf(a, v.z, acc4.z);
            acc4.w = fmaf(a, v.w, acc4.w);
        }
        part[cgr][i4l] = acc4;
        __syncthreads();
        if (tid < 8) {
            float4 sum = part[0][tid];
            #pragma unroll
            for (int g2 = 1; g2 < 32; g2++) {
                float4 p = part[g2][tid];
                sum.x += p.x; sum.y += p.y; sum.z += p.z; sum.w += p.w;
            }
            const float cv = cv_s;
            float4 s;
            s.x = fmaxf(sum.x + cv, 0.f);
            s.y = fmaxf(sum.y + cv, 0.f);
            s.z = fmaxf(sum.z + cv, 0.f);
            s.w = fmaxf(sum.w + cv, 0.f);
            s_s[tid] = s;
        }
        __syncthreads();
        const float4 sv = s_s[i4l];
        #pragma unroll
        for (int j = 0; j < 8; j++) {
            const int c = cgr * 8 + j;
            const float g  = g_s[c];
            const float be = be_s[c];
            const float4 xv = xc[j];
            float4 o;
            o.x = fmaf(sv.x, g, xv.x) + be;
            o.y = fmaf(sv.y, g, xv.y) + be;
            o.z = fmaf(sv.z, g, xv.z) + be;
            o.w = fmaf(sv.w, g, xv.w) + be;
            o4[(size_t)c * NN4 + i4l] = o;
        }
    }
}

extern "C" void kernel_launch(void* const* d_in, const int* in_sizes, int n_in,
                              void* d_out, int out_size, void* d_ws, size_t ws_size,
                              hipStream_t stream) {
    const float* x    = (const float*)d_in[0];
    const float* Wq   = (const float*)d_in[1];
    const float* bq   = (const float*)d_in[2];
    const float* Wk   = (const float*)d_in[3];
    const float* bk   = (const float*)d_in[4];
    const float* Wv   = (const float*)d_in[5];
    const float* bv   = (const float*)d_in[6];
    const float* Wcat = (const float*)d_in[7];
    const float* Wexp = (const float*)d_in[8];
    const float* bexp = (const float*)d_in[9];
    float* out = (float*)d_out;

    float* ws   = (float*)d_ws;
    float* xbar = ws;                       // 2048
    float* Ag   = ws + 2048;                // 256
    float* cstg = ws + 2304;                // 16 (1 + pad)
    unsigned int* cnt = (unsigned int*)(ws + 2320);

    hipMemsetAsync(cnt, 0, sizeof(unsigned int), stream);
    mega<<<GRID, 256, 0, stream>>>(x, Wq, bq, Wk, bk, Wv, bv, Wcat, Wexp, bexp,
                                   out, xbar, Ag, cstg, cnt);
}

// Round 4
// 250.636 us; speedup vs baseline: 1.0753x; 1.0753x over previous
//
#include <hip/hip_runtime.h>

#define CC 256
#define EE 128
#define BB 8
#define NN 3136
#define NN4 784      // NN / 4 (float4 per row)
#define T4 8         // float4 per i-tile (32 spatial positions)
#define NTILES 98    // tiles per batch image
#define GRID 784     // 1 tile per block; <=1024 co-resident guaranteed by launch_bounds
#define SCOPE __HIP_MEMORY_SCOPE_AGENT

__device__ __forceinline__ float waveReduceSum(float v) {
    #pragma unroll
    for (int off = 32; off > 0; off >>= 1) v += __shfl_down(v, off, 64);
    return v;
}

// Single kernel, co-resident grid, manual barrier with RELAXED spin.
//  W   (block 783): A[c], cst  (overlaps others' phase X)
//  X   (all): <=3 xbar rows per block, all loads in flight, one reduce
//  BAR : relaxed spin + one acquire (no per-poll cache invalidate!)
//  G   (per block): u = Wv·xbar_b + bv; g = Wexp·u   (inputs only, L2-hot)
//  OUT (1 tile): s[i] = relu(A·x[b,:,i] + cst); out = x + s*g + bexp
__global__ void __launch_bounds__(256, 4) mega(
        const float* __restrict__ x,
        const float* __restrict__ Wq, const float* __restrict__ bq,
        const float* __restrict__ Wk, const float* __restrict__ bk,
        const float* __restrict__ Wv, const float* __restrict__ bv,
        const float* __restrict__ Wcat, const float* __restrict__ Wexp,
        const float* __restrict__ bexp, float* __restrict__ out,
        float* __restrict__ xbar, float* __restrict__ Ag,
        float* __restrict__ cstg, unsigned int* __restrict__ cnt)
{
    const int blk = blockIdx.x, tid = threadIdx.x;
    const int wid = tid >> 6, lane = tid & 63;

    __shared__ float redm[3][4];
    __shared__ float xb_s[CC];
    __shared__ float u_part[2][EE];
    __shared__ float u_s[EE];
    __shared__ float g_s[CC];
    __shared__ float A_s[CC];
    __shared__ float be_s[CC];
    __shared__ float cv_s;
    __shared__ float4 part2[4][8];
    __shared__ float4 s_s[8];

    // ---- phase W: A & cst (block 783; overlaps phase X of other blocks) ----
    if (blk == GRID - 1) {
        float a = 0.f;
        #pragma unroll 8
        for (int e = 0; e < EE; e++)
            a += Wcat[e] * Wq[e * CC + tid] + Wcat[EE + e] * Wk[e * CC + tid];
        __hip_atomic_store(&Ag[tid], a, __ATOMIC_RELEASE, SCOPE);
        if (tid < 64) {
            float cp = Wcat[tid] * bq[tid] + Wcat[tid + 64] * bq[tid + 64]
                     + Wcat[EE + tid] * bk[tid] + Wcat[EE + tid + 64] * bk[tid + 64];
            cp = waveReduceSum(cp);
            if (tid == 0) __hip_atomic_store(&cstg[0], cp, __ATOMIC_RELEASE, SCOPE);
        }
    }

    // ---- phase X: up to 3 rows per block, no barriers between rows ----
    float racc[3] = {0.f, 0.f, 0.f};
    #pragma unroll
    for (int r = 0; r < 3; r++) {
        const int row = blk + r * GRID;
        if (row < BB * CC) {
            const float4* xr = (const float4*)(x + (size_t)row * NN);
            float a = 0.f;
            for (int i = tid; i < NN4; i += 256) {
                float4 v = xr[i];
                a += (v.x + v.y) + (v.z + v.w);
            }
            racc[r] = a;
        }
    }
    #pragma unroll
    for (int r = 0; r < 3; r++) {
        if (blk + r * GRID < BB * CC) {
            float a = waveReduceSum(racc[r]);
            if (lane == 0) redm[r][wid] = a;
        }
    }
    __syncthreads();
    if (tid < 3) {
        const int row = blk + tid * GRID;
        if (row < BB * CC) {
            float s = (redm[tid][0] + redm[tid][1] + redm[tid][2] + redm[tid][3])
                    * (1.0f / NN);
            __hip_atomic_store(&xbar[row], s, __ATOMIC_RELEASE, SCOPE);
        }
    }

    // ---- barrier: relaxed spin (no invalidate storm), one acquire at exit ----
    __syncthreads();
    if (tid == 0) {
        __hip_atomic_fetch_add(cnt, 1u, __ATOMIC_ACQ_REL, SCOPE);
        while (__hip_atomic_load(cnt, __ATOMIC_RELAXED, SCOPE) < (unsigned)GRID)
            __builtin_amdgcn_s_sleep(8);
        (void)__hip_atomic_load(cnt, __ATOMIC_ACQUIRE, SCOPE);
    }
    __syncthreads();

    // ---- post-barrier data (one-shot acquire loads) ----
    const int b    = blk / NTILES;
    const int tile = blk - b * NTILES;
    xb_s[tid] = __hip_atomic_load(&xbar[b * CC + tid], __ATOMIC_ACQUIRE, SCOPE);
    A_s[tid]  = __hip_atomic_load(&Ag[tid], __ATOMIC_ACQUIRE, SCOPE);
    be_s[tid] = bexp[tid];
    if (tid == 0) cv_s = __hip_atomic_load(&cstg[0], __ATOMIC_ACQUIRE, SCOPE);
    __syncthreads();

    // ---- issue OUT x-tile loads now; G-phase FMAs hide their L3 latency ----
    const int i4l = tid & 7, cgr = tid >> 3;
    const float4* x4 = (const float4*)x + (size_t)b * CC * NN4 + tile * T4;
    float4*       o4 = (float4*)out     + (size_t)b * CC * NN4 + tile * T4;
    float4 xc[8];
    #pragma unroll
    for (int j = 0; j < 8; j++)
        xc[j] = x4[(size_t)(cgr * 8 + j) * NN4 + i4l];

    // ---- phase G: u = Wv·xb + bv (split over 2 halves), g = Wexp·u ----
    {
        const int e = tid & 127, h = tid >> 7;
        const float4* wv4 = (const float4*)(Wv + (size_t)e * CC + h * 128);
        const float* xbh = xb_s + h * 128;
        float up = 0.f;
        #pragma unroll
        for (int i = 0; i < 32; i++) {
            float4 w = wv4[i];
            up = fmaf(w.x, xbh[i * 4 + 0], up);
            up = fmaf(w.y, xbh[i * 4 + 1], up);
            up = fmaf(w.z, xbh[i * 4 + 2], up);
            up = fmaf(w.w, xbh[i * 4 + 3], up);
        }
        u_part[h][e] = up;
    }
    __syncthreads();
    if (tid < EE) u_s[tid] = u_part[0][tid] + u_part[1][tid] + bv[tid];
    __syncthreads();
    {
        const float4* we4 = (const float4*)(Wexp + (size_t)tid * EE);
        float g = 0.f;
        #pragma unroll
        for (int i = 0; i < 32; i++) {
            float4 w = we4[i];
            g = fmaf(w.x, u_s[i * 4 + 0], g);
            g = fmaf(w.y, u_s[i * 4 + 1], g);
            g = fmaf(w.z, u_s[i * 4 + 2], g);
            g = fmaf(w.w, u_s[i * 4 + 3], g);
        }
        g_s[tid] = g;
    }
    __syncthreads();

    // ---- phase OUT: s-partials from registered x-tile, shfl-tree reduce ----
    float4 acc4 = make_float4(0.f, 0.f, 0.f, 0.f);
    #pragma unroll
    for (int j = 0; j < 8; j++) {
        const float a = A_s[cgr * 8 + j];
        const float4 v = xc[j];
        acc4.x = fmaf(a, v.x, acc4.x);
        acc4.y = fmaf(a, v.y, acc4.y);
        acc4.z = fmaf(a, v.z, acc4.z);
        acc4.w = fmaf(a, v.w, acc4.w);
    }
    // reduce over the 8 cgr-groups within each wave (cgr bits = lane bits 3..5)
    #pragma unroll
    for (int m = 8; m <= 32; m <<= 1) {
        acc4.x += __shfl_xor(acc4.x, m, 64);
        acc4.y += __shfl_xor(acc4.y, m, 64);
        acc4.z += __shfl_xor(acc4.z, m, 64);
        acc4.w += __shfl_xor(acc4.w, m, 64);
    }
    if (lane < 8) part2[wid][lane] = acc4;
    __syncthreads();
    if (tid < 8) {
        float4 sum = part2[0][tid];
        #pragma unroll
        for (int w = 1; w < 4; w++) {
            float4 p = part2[w][tid];
            sum.x += p.x; sum.y += p.y; sum.z += p.z; sum.w += p.w;
        }
        const float cv = cv_s;
        float4 s;
        s.x = fmaxf(sum.x + cv, 0.f);
        s.y = fmaxf(sum.y + cv, 0.f);
        s.z = fmaxf(sum.z + cv, 0.f);
        s.w = fmaxf(sum.w + cv, 0.f);
        s_s[tid] = s;
    }
    __syncthreads();

    const float4 sv = s_s[i4l];
    #pragma unroll
    for (int j = 0; j < 8; j++) {
        const int c = cgr * 8 + j;
        const float g  = g_s[c];
        const float be = be_s[c];
        const float4 xv = xc[j];
        float4 o;
        o.x = fmaf(sv.x, g, xv.x) + be;
        o.y = fmaf(sv.y, g, xv.y) + be;
        o.z = fmaf(sv.z, g, xv.z) + be;
        o.w = fmaf(sv.w, g, xv.w) + be;
        o4[(size_t)c * NN4 + i4l] = o;
    }
}

extern "C" void kernel_launch(void* const* d_in, const int* in_sizes, int n_in,
                              void* d_out, int out_size, void* d_ws, size_t ws_size,
                              hipStream_t stream) {
    const float* x    = (const float*)d_in[0];
    const float* Wq   = (const float*)d_in[1];
    const float* bq   = (const float*)d_in[2];
    const float* Wk   = (const float*)d_in[3];
    const float* bk   = (const float*)d_in[4];
    const float* Wv   = (const float*)d_in[5];
    const float* bv   = (const float*)d_in[6];
    const float* Wcat = (const float*)d_in[7];
    const float* Wexp = (const float*)d_in[8];
    const float* bexp = (const float*)d_in[9];
    float* out = (float*)d_out;

    float* ws   = (float*)d_ws;
    float* xbar = ws;                       // 2048
    float* Ag   = ws + 2048;                // 256
    float* cstg = ws + 2304;                // 16 (1 + pad)
    unsigned int* cnt = (unsigned int*)(ws + 2320);

    hipMemsetAsync(cnt, 0, sizeof(unsigned int), stream);
    mega<<<GRID, 256, 0, stream>>>(x, Wq, bq, Wk, bk, Wv, bv, Wcat, Wexp, bexp,
                                   out, xbar, Ag, cstg, cnt);
}

// Round 5
// 186.029 us; speedup vs baseline: 1.4488x; 1.3473x over previous
//
#include <hip/hip_runtime.h>

#define CC 256
#define EE 128
#define BB 8
#define NN 3136
#define NN4 784      // NN / 4 (float4 per row)
#define T4 8         // float4 per i-tile (32 spatial positions)
#define NTILES 98    // tiles per batch image
#define GRID 784     // 1 tile per block; co-residency guaranteed by launch_bounds(256,4)
#define SCOPE __HIP_MEMORY_SCOPE_AGENT

__device__ __forceinline__ float waveReduceSum(float v) {
    #pragma unroll
    for (int off = 32; off > 0; off >>= 1) v += __shfl_down(v, off, 64);
    return v;
}

// Single kernel, co-resident grid, manual barrier.
// Memory-model discipline (gfx950 multi-XCD): exactly ONE release RMW
// (vmcnt+wbl2) and ONE acquire load (buffer_inv) per block. Everything else
// is plain loads/stores — no per-thread agent-op latency chains.
//  W   (block 783): A[c], cst  (plain stores; overlaps others' phase X)
//  X   (all): <=3 xbar rows per block, plain stores
//  BAR : release fetch_add -> relaxed spin -> one acquire load
//  G   (per block): u = Wv·xbar_b + bv; g = Wexp·u   (L2/L3-hot inputs)
//  OUT (1 tile): s[i] = relu(A·x[b,:,i] + cst); out = x + s*g + bexp
__global__ void __launch_bounds__(256, 4) mega(
        const float* __restrict__ x,
        const float* __restrict__ Wq, const float* __restrict__ bq,
        const float* __restrict__ Wk, const float* __restrict__ bk,
        const float* __restrict__ Wv, const float* __restrict__ bv,
        const float* __restrict__ Wcat, const float* __restrict__ Wexp,
        const float* __restrict__ bexp, float* __restrict__ out,
        float* __restrict__ xbar, float* __restrict__ Ag,
        float* __restrict__ cstg, unsigned int* __restrict__ cnt)
{
    const int blk = blockIdx.x, tid = threadIdx.x;
    const int wid = tid >> 6, lane = tid & 63;

    __shared__ float redm[3][4];
    __shared__ float xb_s[CC];
    __shared__ float u_part[2][EE];
    __shared__ float u_s[EE];
    __shared__ float g_s[CC];
    __shared__ float A_s[CC];
    __shared__ float be_s[CC];
    __shared__ float cv_s;
    __shared__ float4 part2[4][8];
    __shared__ float4 s_s[8];

    // ---- phase W: A & cst (block 783; plain stores) ----
    if (blk == GRID - 1) {
        float a = 0.f;
        #pragma unroll 8
        for (int e = 0; e < EE; e++)
            a += Wcat[e] * Wq[e * CC + tid] + Wcat[EE + e] * Wk[e * CC + tid];
        Ag[tid] = a;
        if (tid < 64) {
            float cp = Wcat[tid] * bq[tid] + Wcat[tid + 64] * bq[tid + 64]
                     + Wcat[EE + tid] * bk[tid] + Wcat[EE + tid + 64] * bk[tid + 64];
            cp = waveReduceSum(cp);
            if (tid == 0) cstg[0] = cp;
        }
    }

    // ---- phase X: up to 3 rows per block, plain stores, no agent ops ----
    float racc[3] = {0.f, 0.f, 0.f};
    #pragma unroll
    for (int r = 0; r < 3; r++) {
        const int row = blk + r * GRID;
        if (row < BB * CC) {
            const float4* xr = (const float4*)(x + (size_t)row * NN);
            float a = 0.f;
            for (int i = tid; i < NN4; i += 256) {
                float4 v = xr[i];
                a += (v.x + v.y) + (v.z + v.w);
            }
            racc[r] = a;
        }
    }
    #pragma unroll
    for (int r = 0; r < 3; r++) {
        if (blk + r * GRID < BB * CC) {
            float a = waveReduceSum(racc[r]);
            if (lane == 0) redm[r][wid] = a;
        }
    }
    __syncthreads();
    if (tid < 3) {
        const int row = blk + tid * GRID;
        if (row < BB * CC)
            xbar[row] = (redm[tid][0] + redm[tid][1] + redm[tid][2] + redm[tid][3])
                      * (1.0f / NN);
    }

    // ---- barrier: ONE release RMW, relaxed spin, ONE acquire load ----
    __syncthreads();
    if (tid == 0) {
        __hip_atomic_fetch_add(cnt, 1u, __ATOMIC_RELEASE, SCOPE);   // publishes plain stores
        while (__hip_atomic_load(cnt, __ATOMIC_RELAXED, SCOPE) < (unsigned)GRID)
            __builtin_amdgcn_s_sleep(16);
        (void)__hip_atomic_load(cnt, __ATOMIC_ACQUIRE, SCOPE);      // one buffer_inv
    }
    __syncthreads();

    // ---- post-barrier data: PLAIN loads (pipelined, no waitcnt chain) ----
    const int b    = blk / NTILES;
    const int tile = blk - b * NTILES;
    xb_s[tid] = xbar[b * CC + tid];
    A_s[tid]  = Ag[tid];
    be_s[tid] = bexp[tid];
    if (tid == 0) cv_s = cstg[0];
    __syncthreads();

    // ---- issue OUT x-tile loads now; G-phase FMAs hide their L3 latency ----
    const int i4l = tid & 7, cgr = tid >> 3;
    const float4* x4 = (const float4*)x + (size_t)b * CC * NN4 + tile * T4;
    float4*       o4 = (float4*)out     + (size_t)b * CC * NN4 + tile * T4;
    float4 xc[8];
    #pragma unroll
    for (int j = 0; j < 8; j++)
        xc[j] = x4[(size_t)(cgr * 8 + j) * NN4 + i4l];

    // ---- phase G: u = Wv·xb + bv (2 halves), g = Wexp·u ----
    {
        const int e = tid & 127, h = tid >> 7;
        const float4* wv4 = (const float4*)(Wv + (size_t)e * CC + h * 128);
        const float* xbh = xb_s + h * 128;
        float up = 0.f;
        #pragma unroll
        for (int i = 0; i < 32; i++) {
            float4 w = wv4[i];
            up = fmaf(w.x, xbh[i * 4 + 0], up);
            up = fmaf(w.y, xbh[i * 4 + 1], up);
            up = fmaf(w.z, xbh[i * 4 + 2], up);
            up = fmaf(w.w, xbh[i * 4 + 3], up);
        }
        u_part[h][e] = up;
    }
    __syncthreads();
    if (tid < EE) u_s[tid] = u_part[0][tid] + u_part[1][tid] + bv[tid];
    __syncthreads();
    {
        const float4* we4 = (const float4*)(Wexp + (size_t)tid * EE);
        float g = 0.f;
        #pragma unroll
        for (int i = 0; i < 32; i++) {
            float4 w = we4[i];
            g = fmaf(w.x, u_s[i * 4 + 0], g);
            g = fmaf(w.y, u_s[i * 4 + 1], g);
            g = fmaf(w.z, u_s[i * 4 + 2], g);
            g = fmaf(w.w, u_s[i * 4 + 3], g);
        }
        g_s[tid] = g;
    }
    __syncthreads();

    // ---- phase OUT: s-partials from registered x-tile, shfl-tree reduce ----
    float4 acc4 = make_float4(0.f, 0.f, 0.f, 0.f);
    #pragma unroll
    for (int j = 0; j < 8; j++) {
        const float a = A_s[cgr * 8 + j];
        const float4 v = xc[j];
        acc4.x = fmaf(a, v.x, acc4.x);
        acc4.y = fmaf(a, v.y, acc4.y);
        acc4.z = fmaf(a, v.z, acc4.z);
        acc4.w = fmaf(a, v.w, acc4.w);
    }
    #pragma unroll
    for (int m = 8; m <= 32; m <<= 1) {
        acc4.x += __shfl_xor(acc4.x, m, 64);
        acc4.y += __shfl_xor(acc4.y, m, 64);
        acc4.z += __shfl_xor(acc4.z, m, 64);
        acc4.w += __shfl_xor(acc4.w, m, 64);
    }
    if (lane < 8) part2[wid][lane] = acc4;
    __syncthreads();
    if (tid < 8) {
        float4 sum = part2[0][tid];
        #pragma unroll
        for (int w = 1; w < 4; w++) {
            float4 p = part2[w][tid];
            sum.x += p.x; sum.y += p.y; sum.z += p.z; sum.w += p.w;
        }
        const float cv = cv_s;
        float4 s;
        s.x = fmaxf(sum.x + cv, 0.f);
        s.y = fmaxf(sum.y + cv, 0.f);
        s.z = fmaxf(sum.z + cv, 0.f);
        s.w = fmaxf(sum.w + cv, 0.f);
        s_s[tid] = s;
    }
    __syncthreads();

    const float4 sv = s_s[i4l];
    #pragma unroll
    for (int j = 0; j < 8; j++) {
        const int c = cgr * 8 + j;
        const float g  = g_s[c];
        const float be = be_s[c];
        const float4 xv = xc[j];
        float4 o;
        o.x = fmaf(sv.x, g, xv.x) + be;
        o.y = fmaf(sv.y, g, xv.y) + be;
        o.z = fmaf(sv.z, g, xv.z) + be;
        o.w = fmaf(sv.w, g, xv.w) + be;
        o4[(size_t)c * NN4 + i4l] = o;
    }
}

extern "C" void kernel_launch(void* const* d_in, const int* in_sizes, int n_in,
                              void* d_out, int out_size, void* d_ws, size_t ws_size,
                              hipStream_t stream) {
    const float* x    = (const float*)d_in[0];
    const float* Wq   = (const float*)d_in[1];
    const float* bq   = (const float*)d_in[2];
    const float* Wk   = (const float*)d_in[3];
    const float* bk   = (const float*)d_in[4];
    const float* Wv   = (const float*)d_in[5];
    const float* bv   = (const float*)d_in[6];
    const float* Wcat = (const float*)d_in[7];
    const float* Wexp = (const float*)d_in[8];
    const float* bexp = (const float*)d_in[9];
    float* out = (float*)d_out;

    float* ws   = (float*)d_ws;
    float* xbar = ws;                       // 2048
    float* Ag   = ws + 2048;                // 256
    float* cstg = ws + 2304;                // 16 (1 + pad)
    unsigned int* cnt = (unsigned int*)(ws + 2320);

    hipMemsetAsync(cnt, 0, sizeof(unsigned int), stream);
    mega<<<GRID, 256, 0, stream>>>(x, Wq, bq, Wk, bk, Wv, bv, Wcat, Wexp, bexp,
                                   out, xbar, Ag, cstg, cnt);
}

// Round 6
// 139.140 us; speedup vs baseline: 1.9370x; 1.3370x over previous
//
#include <hip/hip_runtime.h>

#define CC 256
#define EE 128
#define BB 8
#define NN 3136
#define NN4 784      // NN / 4 (float4 per row)
#define T4 8         // float4 per i-tile (32 spatial positions)
#define NTILES 98    // tiles per batch image

__device__ __forceinline__ float waveReduceSum(float v) {
    #pragma unroll
    for (int off = 32; off > 0; off >>= 1) v += __shfl_down(v, off, 64);
    return v;
}

// kA: block 0        -> A[c] = Wcat[:E]·Wq[:,c] + Wcat[E:]·Wk[:,c];  cst
//     blocks 1..2048 -> xbar[row] = mean_i x[row, i]   (one row per block,
//                       2048 blocks = 8 blocks/CU -> full occupancy, BW-bound)
// Weight-prep at the FRONT of the grid: starts first, overlaps the sweep.
__global__ void __launch_bounds__(256) kA(
        const float* __restrict__ x,
        const float* __restrict__ Wq, const float* __restrict__ bq,
        const float* __restrict__ Wk, const float* __restrict__ bk,
        const float* __restrict__ Wcat,
        float* __restrict__ xbar, float* __restrict__ Ag, float* __restrict__ cstg) {
    const int blk = blockIdx.x;
    const int tid = threadIdx.x;
    if (blk == 0) {
        float a = 0.f;
        #pragma unroll 8
        for (int e = 0; e < EE; e++)
            a += Wcat[e] * Wq[e * CC + tid] + Wcat[EE + e] * Wk[e * CC + tid];
        Ag[tid] = a;
        if (tid < 64) {
            float cp = Wcat[tid] * bq[tid] + Wcat[tid + 64] * bq[tid + 64]
                     + Wcat[EE + tid] * bk[tid] + Wcat[EE + tid + 64] * bk[tid + 64];
            cp = waveReduceSum(cp);
            if (tid == 0) cstg[0] = cp;
        }
    } else {
        const int row = blk - 1;                     // 0..2047
        const float4* xr = (const float4*)(x + (size_t)row * NN);
        float acc = 0.f;
        for (int i = tid; i < NN4; i += 256) {
            float4 v = xr[i];
            acc += (v.x + v.y) + (v.z + v.w);
        }
        acc = waveReduceSum(acc);
        __shared__ float red[4];
        const int wid = tid >> 6, lane = tid & 63;
        if (lane == 0) red[wid] = acc;
        __syncthreads();
        if (tid == 0)
            xbar[row] = (red[0] + red[1] + red[2] + red[3]) * (1.0f / NN);
    }
}

// kB: block = (b, tile). Factored per-block gexp (no M precompute, no barrier):
//   u[e] = Wv[e,:]·xbar_b + bv[e];  g[c] = Wexp[c,:]·u      (weights L2-hot)
//   s[i] = relu(sum_c A[c]*x[b,c,i] + cst)
//   out  = x + s*g + bexp
// x-tile loads issued BEFORE the g-dots so their L3 latency hides under FMAs.
__global__ void __launch_bounds__(256, 4) kB(
        const float* __restrict__ x, const float* __restrict__ xbar,
        const float* __restrict__ Wv, const float* __restrict__ bv,
        const float* __restrict__ Wexp, const float* __restrict__ bexp,
        const float* __restrict__ Ag, const float* __restrict__ cstg,
        float* __restrict__ out) {
    const int b    = blockIdx.x / NTILES;
    const int tile = blockIdx.x - b * NTILES;
    const int tid  = threadIdx.x;
    const int wid = tid >> 6, lane = tid & 63;
    const int i4l = tid & 7, cgr = tid >> 3;   // 8 i-slots x 32 c-groups (8 ch each)

    __shared__ float xb_s[CC];
    __shared__ float u_part[2][EE];
    __shared__ float u_s[EE];
    __shared__ float g_s[CC];
    __shared__ float A_s[CC];
    __shared__ float be_s[CC];
    __shared__ float cv_s;
    __shared__ float4 part2[4][8];
    __shared__ float4 s_s[8];

    xb_s[tid] = xbar[b * CC + tid];
    A_s[tid]  = Ag[tid];
    be_s[tid] = bexp[tid];
    if (tid == 0) cv_s = cstg[0];
    __syncthreads();

    // issue the 8 x-tile loads first (L3-warm from kA); G-dots hide latency
    const float4* x4 = (const float4*)x + (size_t)b * CC * NN4 + tile * T4;
    float4*       o4 = (float4*)out     + (size_t)b * CC * NN4 + tile * T4;
    float4 xc[8];
    #pragma unroll
    for (int j = 0; j < 8; j++)
        xc[j] = x4[(size_t)(cgr * 8 + j) * NN4 + i4l];

    // ---- u = Wv·xb + bv (two halves across 256 threads) ----
    {
        const int e = tid & 127, h = tid >> 7;
        const float4* wv4 = (const float4*)(Wv + (size_t)e * CC + h * 128);
        const float* xbh = xb_s + h * 128;
        float up = 0.f;
        #pragma unroll
        for (int i = 0; i < 32; i++) {
            float4 w = wv4[i];
            up = fmaf(w.x, xbh[i * 4 + 0], up);
            up = fmaf(w.y, xbh[i * 4 + 1], up);
            up = fmaf(w.z, xbh[i * 4 + 2], up);
            up = fmaf(w.w, xbh[i * 4 + 3], up);
        }
        u_part[h][e] = up;
    }
    __syncthreads();
    if (tid < EE) u_s[tid] = u_part[0][tid] + u_part[1][tid] + bv[tid];
    __syncthreads();

    // ---- g[c] = Wexp[c,:]·u ----
    {
        const float4* we4 = (const float4*)(Wexp + (size_t)tid * EE);
        float g = 0.f;
        #pragma unroll
        for (int i = 0; i < 32; i++) {
            float4 w = we4[i];
            g = fmaf(w.x, u_s[i * 4 + 0], g);
            g = fmaf(w.y, u_s[i * 4 + 1], g);
            g = fmaf(w.z, u_s[i * 4 + 2], g);
            g = fmaf(w.w, u_s[i * 4 + 3], g);
        }
        g_s[tid] = g;
    }
    __syncthreads();

    // ---- s-partials from registered x-tile, shfl-tree + LDS reduce ----
    float4 acc4 = make_float4(0.f, 0.f, 0.f, 0.f);
    #pragma unroll
    for (int j = 0; j < 8; j++) {
        const float a = A_s[cgr * 8 + j];
        const float4 v = xc[j];
        acc4.x = fmaf(a, v.x, acc4.x);
        acc4.y = fmaf(a, v.y, acc4.y);
        acc4.z = fmaf(a, v.z, acc4.z);
        acc4.w = fmaf(a, v.w, acc4.w);
    }
    #pragma unroll
    for (int m = 8; m <= 32; m <<= 1) {
        acc4.x += __shfl_xor(acc4.x, m, 64);
        acc4.y += __shfl_xor(acc4.y, m, 64);
        acc4.z += __shfl_xor(acc4.z, m, 64);
        acc4.w += __shfl_xor(acc4.w, m, 64);
    }
    if (lane < 8) part2[wid][lane] = acc4;
    __syncthreads();
    if (tid < 8) {
        float4 sum = part2[0][tid];
        #pragma unroll
        for (int w = 1; w < 4; w++) {
            float4 p = part2[w][tid];
            sum.x += p.x; sum.y += p.y; sum.z += p.z; sum.w += p.w;
        }
        const float cv = cv_s;
        float4 s;
        s.x = fmaxf(sum.x + cv, 0.f);
        s.y = fmaxf(sum.y + cv, 0.f);
        s.z = fmaxf(sum.z + cv, 0.f);
        s.w = fmaxf(sum.w + cv, 0.f);
        s_s[tid] = s;
    }
    __syncthreads();

    const float4 sv = s_s[i4l];
    #pragma unroll
    for (int j = 0; j < 8; j++) {
        const int c = cgr * 8 + j;
        const float g  = g_s[c];
        const float be = be_s[c];
        const float4 xv = xc[j];
        float4 o;
        o.x = fmaf(sv.x, g, xv.x) + be;
        o.y = fmaf(sv.y, g, xv.y) + be;
        o.z = fmaf(sv.z, g, xv.z) + be;
        o.w = fmaf(sv.w, g, xv.w) + be;
        o4[(size_t)c * NN4 + i4l] = o;
    }
}

extern "C" void kernel_launch(void* const* d_in, const int* in_sizes, int n_in,
                              void* d_out, int out_size, void* d_ws, size_t ws_size,
                              hipStream_t stream) {
    const float* x    = (const float*)d_in[0];
    const float* Wq   = (const float*)d_in[1];
    const float* bq   = (const float*)d_in[2];
    const float* Wk   = (const float*)d_in[3];
    const float* bk   = (const float*)d_in[4];
    const float* Wv   = (const float*)d_in[5];
    const float* bv   = (const float*)d_in[6];
    const float* Wcat = (const float*)d_in[7];
    const float* Wexp = (const float*)d_in[8];
    const float* bexp = (const float*)d_in[9];
    float* out = (float*)d_out;

    float* ws   = (float*)d_ws;
    float* xbar = ws;                       // 2048
    float* Ag   = ws + 2048;                // 256
    float* cstg = ws + 2304;                // 1 (+pad)

    kA<<<1 + BB * CC, 256, 0, stream>>>(x, Wq, bq, Wk, bk, Wcat, xbar, Ag, cstg);
    kB<<<BB * NTILES, 256, 0, stream>>>(x, xbar, Wv, bv, Wexp, bexp, Ag, cstg, out);
}

// Round 7
// 116.209 us; speedup vs baseline: 2.3192x; 1.1973x over previous
//
#include <hip/hip_runtime.h>

#define CC 256
#define EE 128
#define BB 8
#define NN 3136
#define NN4 784      // NN / 4 (float4 per row)
#define T4 8         // float4 per i-tile (32 spatial positions)
#define NTILES 98    // tiles per batch image

__device__ __forceinline__ float waveReduceSum(float v) {
    #pragma unroll
    for (int off = 32; off > 0; off >>= 1) v += __shfl_down(v, off, 64);
    return v;
}

// kA: block 0        -> A[c] = Wcat[:E]·Wq[:,c] + Wcat[E:]·Wk[:,c];  cst
//     blocks 1..2048 -> xbar[row] = mean_i x[row, i]  (one row/block, BW-bound)
__global__ void __launch_bounds__(256) kA(
        const float* __restrict__ x,
        const float* __restrict__ Wq, const float* __restrict__ bq,
        const float* __restrict__ Wk, const float* __restrict__ bk,
        const float* __restrict__ Wcat,
        float* __restrict__ xbar, float* __restrict__ Ag, float* __restrict__ cstg) {
    const int blk = blockIdx.x;
    const int tid = threadIdx.x;
    if (blk == 0) {
        float a = 0.f;
        #pragma unroll 8
        for (int e = 0; e < EE; e++)
            a += Wcat[e] * Wq[e * CC + tid] + Wcat[EE + e] * Wk[e * CC + tid];
        Ag[tid] = a;
        if (tid < 64) {
            float cp = Wcat[tid] * bq[tid] + Wcat[tid + 64] * bq[tid + 64]
                     + Wcat[EE + tid] * bk[tid] + Wcat[EE + tid + 64] * bk[tid + 64];
            cp = waveReduceSum(cp);
            if (tid == 0) cstg[0] = cp;
        }
    } else {
        const int row = blk - 1;                     // 0..2047
        const float4* xr = (const float4*)(x + (size_t)row * NN);
        float acc = 0.f;
        for (int i = tid; i < NN4; i += 256) {
            float4 v = xr[i];
            acc += (v.x + v.y) + (v.z + v.w);
        }
        acc = waveReduceSum(acc);
        __shared__ float red[4];
        const int wid = tid >> 6, lane = tid & 63;
        if (lane == 0) red[wid] = acc;
        __syncthreads();
        if (tid == 0)
            xbar[row] = (red[0] + red[1] + red[2] + red[3]) * (1.0f / NN);
    }
}

// kG: 8 blocks, one per batch image. Weights read ONCE per image (2 MB total
// instead of round-6's 200 MB per-tile redundancy):
//   u[e] = Wv[e,:]·xbar_b + bv[e];   gexp[b,c] = Wexp[c,:]·u
__global__ void __launch_bounds__(256) kG(
        const float* __restrict__ xbar,
        const float* __restrict__ Wv, const float* __restrict__ bv,
        const float* __restrict__ Wexp, float* __restrict__ gexp) {
    const int b = blockIdx.x;
    const int tid = threadIdx.x;

    __shared__ float xb_s[CC];
    __shared__ float u_part[2][EE];
    __shared__ float u_s[EE];

    xb_s[tid] = xbar[b * CC + tid];
    __syncthreads();

    {   // u = Wv·xb + bv  (two halves across 256 threads)
        const int e = tid & 127, h = tid >> 7;
        const float4* wv4 = (const float4*)(Wv + (size_t)e * CC + h * 128);
        const float* xbh = xb_s + h * 128;
        float up = 0.f;
        #pragma unroll
        for (int i = 0; i < 32; i++) {
            float4 w = wv4[i];
            up = fmaf(w.x, xbh[i * 4 + 0], up);
            up = fmaf(w.y, xbh[i * 4 + 1], up);
            up = fmaf(w.z, xbh[i * 4 + 2], up);
            up = fmaf(w.w, xbh[i * 4 + 3], up);
        }
        u_part[h][e] = up;
    }
    __syncthreads();
    if (tid < EE) u_s[tid] = u_part[0][tid] + u_part[1][tid] + bv[tid];
    __syncthreads();

    {   // gexp[b,c] = Wexp[c,:]·u
        const float4* we4 = (const float4*)(Wexp + (size_t)tid * EE);
        float g = 0.f;
        #pragma unroll
        for (int i = 0; i < 32; i++) {
            float4 w = we4[i];
            g = fmaf(w.x, u_s[i * 4 + 0], g);
            g = fmaf(w.y, u_s[i * 4 + 1], g);
            g = fmaf(w.z, u_s[i * 4 + 2], g);
            g = fmaf(w.w, u_s[i * 4 + 3], g);
        }
        gexp[b * CC + tid] = g;
    }
}

// kB: pure streaming output. block = (b, tile of 8 float4 = 32 positions).
//   s[i] = relu(sum_c A[c]*x[b,c,i] + cst);  out = x + s*gexp[b,:] + bexp
// No weight reads; gexp precomputed. Full occupancy (8 blocks/CU).
__global__ void __launch_bounds__(256, 8) kB(
        const float* __restrict__ x, const float* __restrict__ gexp,
        const float* __restrict__ bexp, const float* __restrict__ Ag,
        const float* __restrict__ cstg, float* __restrict__ out) {
    const int b    = blockIdx.x / NTILES;
    const int tile = blockIdx.x - b * NTILES;
    const int tid  = threadIdx.x;
    const int wid = tid >> 6, lane = tid & 63;
    const int i4l = tid & 7, cgr = tid >> 3;   // 8 i-slots x 32 c-groups

    __shared__ float A_s[CC];
    __shared__ float g_s[CC];
    __shared__ float be_s[CC];
    __shared__ float cv_s;
    __shared__ float4 part2[4][8];
    __shared__ float4 s_s[8];

    A_s[tid]  = Ag[tid];
    g_s[tid]  = gexp[b * CC + tid];
    be_s[tid] = bexp[tid];
    if (tid == 0) cv_s = cstg[0];
    __syncthreads();

    const float4* x4 = (const float4*)x + (size_t)b * CC * NN4 + tile * T4;
    float4*       o4 = (float4*)out     + (size_t)b * CC * NN4 + tile * T4;

    float4 xc[8];
    float4 acc4 = make_float4(0.f, 0.f, 0.f, 0.f);
    #pragma unroll
    for (int j = 0; j < 8; j++) {
        const int c = cgr * 8 + j;
        float4 v = x4[(size_t)c * NN4 + i4l];
        xc[j] = v;
        const float a = A_s[c];
        acc4.x = fmaf(a, v.x, acc4.x);
        acc4.y = fmaf(a, v.y, acc4.y);
        acc4.z = fmaf(a, v.z, acc4.z);
        acc4.w = fmaf(a, v.w, acc4.w);
    }
    #pragma unroll
    for (int m = 8; m <= 32; m <<= 1) {
        acc4.x += __shfl_xor(acc4.x, m, 64);
        acc4.y += __shfl_xor(acc4.y, m, 64);
        acc4.z += __shfl_xor(acc4.z, m, 64);
        acc4.w += __shfl_xor(acc4.w, m, 64);
    }
    if (lane < 8) part2[wid][lane] = acc4;
    __syncthreads();
    if (tid < 8) {
        float4 sum = part2[0][tid];
        #pragma unroll
        for (int w = 1; w < 4; w++) {
            float4 p = part2[w][tid];
            sum.x += p.x; sum.y += p.y; sum.z += p.z; sum.w += p.w;
        }
        const float cv = cv_s;
        float4 s;
        s.x = fmaxf(sum.x + cv, 0.f);
        s.y = fmaxf(sum.y + cv, 0.f);
        s.z = fmaxf(sum.z + cv, 0.f);
        s.w = fmaxf(sum.w + cv, 0.f);
        s_s[tid] = s;
    }
    __syncthreads();

    const float4 sv = s_s[i4l];
    #pragma unroll
    for (int j = 0; j < 8; j++) {
        const int c = cgr * 8 + j;
        const float g  = g_s[c];
        const float be = be_s[c];
        const float4 xv = xc[j];
        float4 o;
        o.x = fmaf(sv.x, g, xv.x) + be;
        o.y = fmaf(sv.y, g, xv.y) + be;
        o.z = fmaf(sv.z, g, xv.z) + be;
        o.w = fmaf(sv.w, g, xv.w) + be;
        o4[(size_t)c * NN4 + i4l] = o;
    }
}

extern "C" void kernel_launch(void* const* d_in, const int* in_sizes, int n_in,
                              void* d_out, int out_size, void* d_ws, size_t ws_size,
                              hipStream_t stream) {
    const float* x    = (const float*)d_in[0];
    const float* Wq   = (const float*)d_in[1];
    const float* bq   = (const float*)d_in[2];
    const float* Wk   = (const float*)d_in[3];
    const float* bk   = (const float*)d_in[4];
    const float* Wv   = (const float*)d_in[5];
    const float* bv   = (const float*)d_in[6];
    const float* Wcat = (const float*)d_in[7];
    const float* Wexp = (const float*)d_in[8];
    const float* bexp = (const float*)d_in[9];
    float* out = (float*)d_out;

    float* ws   = (float*)d_ws;
    float* xbar = ws;                       // 2048
    float* Ag   = ws + 2048;                // 256
    float* cstg = ws + 2304;                // 1 (+pad)
    float* gexp = ws + 2320;                // 2048

    kA<<<1 + BB * CC, 256, 0, stream>>>(x, Wq, bq, Wk, bk, Wcat, xbar, Ag, cstg);
    kG<<<BB, 256, 0, stream>>>(xbar, Wv, bv, Wexp, gexp);
    kB<<<BB * NTILES, 256, 0, stream>>>(x, gexp, bexp, Ag, cstg, out);
}

// Round 8
// 112.342 us; speedup vs baseline: 2.3990x; 1.0344x over previous
//
#include <hip/hip_runtime.h>

#define CC 256
#define EE 128
#define BB 8
#define NN 3136
#define NN4 784      // NN / 4 (float4 per row)
#define T4 8         // float4 per i-tile (32 spatial positions)
#define NTILES 98    // tiles per batch image

__device__ __forceinline__ float waveReduceSum(float v) {
    #pragma unroll
    for (int off = 32; off > 0; off >>= 1) v += __shfl_down(v, off, 64);
    return v;
}

// kA: PURE xbar sweep. One WAVE per row: 512 blocks x 4 independent waves,
// no LDS, no __syncthreads, 12 independent 1KB-coalesced loads in flight
// per wave, one shfl-tree reduce. (A/cst prep moved to kG's spare blocks.)
__global__ void __launch_bounds__(256) kA(
        const float* __restrict__ x, float* __restrict__ xbar) {
    const int tid  = threadIdx.x;
    const int wid  = tid >> 6, lane = tid & 63;
    const int row  = blockIdx.x * 4 + wid;           // 0..2047
    const float4* xr = (const float4*)(x + (size_t)row * NN);

    float acc = 0.f;
    #pragma unroll
    for (int k = 0; k < 12; k++) {                   // 12*64 = 768 float4
        float4 v = xr[lane + (k << 6)];
        acc += (v.x + v.y) + (v.z + v.w);
    }
    if (lane < 16) {                                 // tail: 784-768 = 16
        float4 v = xr[768 + lane];
        acc += (v.x + v.y) + (v.z + v.w);
    }
    acc = waveReduceSum(acc);
    if (lane == 0) xbar[row] = acc * (1.0f / NN);
}

// kG: 9 blocks. b<8: per-image factored gexp (weights read once per image):
//   u[e] = Wv[e,:]·xbar_b + bv[e];   gexp[b,c] = Wexp[c,:]·u
// b==8: A[c] = Wcat[:E]·Wq[:,c] + Wcat[E:]·Wk[:,c];  cst
__global__ void __launch_bounds__(256) kG(
        const float* __restrict__ xbar,
        const float* __restrict__ Wv, const float* __restrict__ bv,
        const float* __restrict__ Wexp,
        const float* __restrict__ Wq, const float* __restrict__ bq,
        const float* __restrict__ Wk, const float* __restrict__ bk,
        const float* __restrict__ Wcat,
        float* __restrict__ gexp, float* __restrict__ Ag, float* __restrict__ cstg) {
    const int b = blockIdx.x;
    const int tid = threadIdx.x;

    if (b == BB) {   // A & cst
        float a = 0.f;
        #pragma unroll 8
        for (int e = 0; e < EE; e++)
            a += Wcat[e] * Wq[e * CC + tid] + Wcat[EE + e] * Wk[e * CC + tid];
        Ag[tid] = a;
        if (tid < 64) {
            float cp = Wcat[tid] * bq[tid] + Wcat[tid + 64] * bq[tid + 64]
                     + Wcat[EE + tid] * bk[tid] + Wcat[EE + tid + 64] * bk[tid + 64];
            cp = waveReduceSum(cp);
            if (tid == 0) cstg[0] = cp;
        }
        return;
    }

    __shared__ float xb_s[CC];
    __shared__ float u_part[2][EE];
    __shared__ float u_s[EE];

    xb_s[tid] = xbar[b * CC + tid];
    __syncthreads();

    {   // u = Wv·xb + bv  (two halves across 256 threads)
        const int e = tid & 127, h = tid >> 7;
        const float4* wv4 = (const float4*)(Wv + (size_t)e * CC + h * 128);
        const float* xbh = xb_s + h * 128;
        float up = 0.f;
        #pragma unroll
        for (int i = 0; i < 32; i++) {
            float4 w = wv4[i];
            up = fmaf(w.x, xbh[i * 4 + 0], up);
            up = fmaf(w.y, xbh[i * 4 + 1], up);
            up = fmaf(w.z, xbh[i * 4 + 2], up);
            up = fmaf(w.w, xbh[i * 4 + 3], up);
        }
        u_part[h][e] = up;
    }
    __syncthreads();
    if (tid < EE) u_s[tid] = u_part[0][tid] + u_part[1][tid] + bv[tid];
    __syncthreads();

    {   // gexp[b,c] = Wexp[c,:]·u
        const float4* we4 = (const float4*)(Wexp + (size_t)tid * EE);
        float g = 0.f;
        #pragma unroll
        for (int i = 0; i < 32; i++) {
            float4 w = we4[i];
            g = fmaf(w.x, u_s[i * 4 + 0], g);
            g = fmaf(w.y, u_s[i * 4 + 1], g);
            g = fmaf(w.z, u_s[i * 4 + 2], g);
            g = fmaf(w.w, u_s[i * 4 + 3], g);
        }
        gexp[b * CC + tid] = g;
    }
}

// kB: pure streaming output. block = (b, tile of 8 float4 = 32 positions).
// x-tile loads issued FIRST so their HBM/L3 latency overlaps the LDS staging
// loads (A/g/be) — one latency exposure instead of two (R6-best ordering).
__global__ void __launch_bounds__(256, 8) kB(
        const float* __restrict__ x, const float* __restrict__ gexp,
        const float* __restrict__ bexp, const float* __restrict__ Ag,
        const float* __restrict__ cstg, float* __restrict__ out) {
    const int b    = blockIdx.x / NTILES;
    const int tile = blockIdx.x - b * NTILES;
    const int tid  = threadIdx.x;
    const int wid = tid >> 6, lane = tid & 63;
    const int i4l = tid & 7, cgr = tid >> 3;   // 8 i-slots x 32 c-groups

    __shared__ float A_s[CC];
    __shared__ float g_s[CC];
    __shared__ float be_s[CC];
    __shared__ float cv_s;
    __shared__ float4 part2[4][8];
    __shared__ float4 s_s[8];

    // issue the 8 x-tile loads first
    const float4* x4 = (const float4*)x + (size_t)b * CC * NN4 + tile * T4;
    float4*       o4 = (float4*)out     + (size_t)b * CC * NN4 + tile * T4;
    float4 xc[8];
    #pragma unroll
    for (int j = 0; j < 8; j++)
        xc[j] = x4[(size_t)(cgr * 8 + j) * NN4 + i4l];

    // LDS staging overlaps the x-tile latency
    A_s[tid]  = Ag[tid];
    g_s[tid]  = gexp[b * CC + tid];
    be_s[tid] = bexp[tid];
    if (tid == 0) cv_s = cstg[0];
    __syncthreads();

    float4 acc4 = make_float4(0.f, 0.f, 0.f, 0.f);
    #pragma unroll
    for (int j = 0; j < 8; j++) {
        const float a = A_s[cgr * 8 + j];
        const float4 v = xc[j];
        acc4.x = fmaf(a, v.x, acc4.x);
        acc4.y = fmaf(a, v.y, acc4.y);
        acc4.z = fmaf(a, v.z, acc4.z);
        acc4.w = fmaf(a, v.w, acc4.w);
    }
    #pragma unroll
    for (int m = 8; m <= 32; m <<= 1) {
        acc4.x += __shfl_xor(acc4.x, m, 64);
        acc4.y += __shfl_xor(acc4.y, m, 64);
        acc4.z += __shfl_xor(acc4.z, m, 64);
        acc4.w += __shfl_xor(acc4.w, m, 64);
    }
    if (lane < 8) part2[wid][lane] = acc4;
    __syncthreads();
    if (tid < 8) {
        float4 sum = part2[0][tid];
        #pragma unroll
        for (int w = 1; w < 4; w++) {
            float4 p = part2[w][tid];
            sum.x += p.x; sum.y += p.y; sum.z += p.z; sum.w += p.w;
        }
        const float cv = cv_s;
        float4 s;
        s.x = fmaxf(sum.x + cv, 0.f);
        s.y = fmaxf(sum.y + cv, 0.f);
        s.z = fmaxf(sum.z + cv, 0.f);
        s.w = fmaxf(sum.w + cv, 0.f);
        s_s[tid] = s;
    }
    __syncthreads();

    const float4 sv = s_s[i4l];
    #pragma unroll
    for (int j = 0; j < 8; j++) {
        const int c = cgr * 8 + j;
        const float g  = g_s[c];
        const float be = be_s[c];
        const float4 xv = xc[j];
        float4 o;
        o.x = fmaf(sv.x, g, xv.x) + be;
        o.y = fmaf(sv.y, g, xv.y) + be;
        o.z = fmaf(sv.z, g, xv.z) + be;
        o.w = fmaf(sv.w, g, xv.w) + be;
        o4[(size_t)c * NN4 + i4l] = o;
    }
}

extern "C" void kernel_launch(void* const* d_in, const int* in_sizes, int n_in,
                              void* d_out, int out_size, void* d_ws, size_t ws_size,
                              hipStream_t stream) {
    const float* x    = (const float*)d_in[0];
    const float* Wq   = (const float*)d_in[1];
    const float* bq   = (const float*)d_in[2];
    const float* Wk   = (const float*)d_in[3];
    const float* bk   = (const float*)d_in[4];
    const float* Wv   = (const float*)d_in[5];
    const float* bv   = (const float*)d_in[6];
    const float* Wcat = (const float*)d_in[7];
    const float* Wexp = (const float*)d_in[8];
    const float* bexp = (const float*)d_in[9];
    float* out = (float*)d_out;

    float* ws   = (float*)d_ws;
    float* xbar = ws;                       // 2048
    float* Ag   = ws + 2048;                // 256
    float* cstg = ws + 2304;                // 1 (+pad)
    float* gexp = ws + 2320;                // 2048

    kA<<<512, 256, 0, stream>>>(x, xbar);
    kG<<<BB + 1, 256, 0, stream>>>(xbar, Wv, bv, Wexp, Wq, bq, Wk, bk, Wcat,
                                   gexp, Ag, cstg);
    kB<<<BB * NTILES, 256, 0, stream>>>(x, gexp, bexp, Ag, cstg, out);
}